// Round 1
// baseline (1379.119 us; speedup 1.0000x reference)
//
#include <hip/hip_runtime.h>
#include <cstdint>
#include <cstddef>

// Problem constants (fixed by the reference)
#define NN 50000
#define EE 400000
#define FIN 128
#define HH 3
#define DD 64
#define GG 64
#define PP 64
#define HD 192   // H*D

__device__ inline float wsum(float v) {
#pragma unroll
    for (int m = 32; m > 0; m >>= 1) v += __shfl_xor(v, m, 64);
    return v;
}
__device__ inline float wmax(float v) {
#pragma unroll
    for (int m = 32; m > 0; m >>= 1) v = fmaxf(v, __shfl_xor(v, m, 64));
    return v;
}

// ---------------- CSR build ----------------
__global__ void k_count(const int* __restrict__ dst, int* __restrict__ counts) {
    int e = blockIdx.x * 256 + threadIdx.x;
    if (e < EE) atomicAdd(&counts[dst[e]], 1);
}

__global__ void k_scan_block(const int* __restrict__ in, int* __restrict__ out,
                             int* __restrict__ bsums) {
    __shared__ int tmp[1024];
    int tid = threadIdx.x;
    int i = blockIdx.x * 1024 + tid;
    int v = (i < NN) ? in[i] : 0;
    tmp[tid] = v;
    __syncthreads();
    for (int off = 1; off < 1024; off <<= 1) {
        int t = (tid >= off) ? tmp[tid - off] : 0;
        __syncthreads();
        tmp[tid] += t;
        __syncthreads();
    }
    if (i < NN) out[i] = tmp[tid] - v;       // exclusive within block
    if (tid == 1023) bsums[blockIdx.x] = tmp[1023];
}

__global__ void k_scan_top(int* bsums, int nb) {
    int lane = threadIdx.x;
    int v = (lane < nb) ? bsums[lane] : 0;
    int x = v;
    for (int off = 1; off < 64; off <<= 1) {
        int t = __shfl_up(x, off, 64);
        if (lane >= off) x += t;
    }
    if (lane < nb) bsums[lane] = x - v;      // exclusive
}

__global__ void k_scan_add(int* __restrict__ row_ptr, const int* __restrict__ bsums) {
    int i = blockIdx.x * 1024 + threadIdx.x;
    if (i < NN) row_ptr[i] += bsums[blockIdx.x];
    if (blockIdx.x == 0 && threadIdx.x == 0) row_ptr[NN] = EE;
}

__global__ void k_scatter(const int* __restrict__ src, const int* __restrict__ dst,
                          const int* __restrict__ row_ptr, int* __restrict__ cursor,
                          int* __restrict__ csr_src, int* __restrict__ csr_dst) {
    int e = blockIdx.x * 256 + threadIdx.x;
    if (e >= EE) return;
    int v = dst[e];
    int pos = row_ptr[v] + atomicAdd(&cursor[v], 1);
    csr_src[pos] = src[e];
    csr_dst[pos] = v;
}

// ---------------- fs/fd GEMM: [N,K] @ [K,192] x2 ----------------
template <int K>
__global__ __launch_bounds__(256) void k_gemm_dual(const float* __restrict__ X,
                                                   const float* __restrict__ Ws,
                                                   const float* __restrict__ Wd,
                                                   float* __restrict__ FS,
                                                   float* __restrict__ FD) {
    __shared__ float xs[16][K];
    int tid = threadIdx.x;
    int row0 = blockIdx.x * 16;
    for (int idx = tid; idx < 16 * K; idx += 256) {
        int r = idx / K, k = idx - r * K;
        int row = row0 + r;
        xs[r][k] = (row < NN) ? X[(size_t)row * K + k] : 0.f;
    }
    __syncthreads();
    int tx = tid & 63;
    int ty = tid >> 6;  // 0..3 -> rows ty*4 .. ty*4+3
    float acc[4][6];
#pragma unroll
    for (int i = 0; i < 4; i++)
#pragma unroll
        for (int j = 0; j < 6; j++) acc[i][j] = 0.f;

    for (int k = 0; k < K; k++) {
        float w0 = Ws[k * HD + tx];
        float w1 = Ws[k * HD + tx + 64];
        float w2 = Ws[k * HD + tx + 128];
        float w3 = Wd[k * HD + tx];
        float w4 = Wd[k * HD + tx + 64];
        float w5 = Wd[k * HD + tx + 128];
#pragma unroll
        for (int i = 0; i < 4; i++) {
            float x = xs[ty * 4 + i][k];   // wave-uniform -> LDS broadcast, no conflicts
            acc[i][0] += x * w0; acc[i][1] += x * w1; acc[i][2] += x * w2;
            acc[i][3] += x * w3; acc[i][4] += x * w4; acc[i][5] += x * w5;
        }
    }
#pragma unroll
    for (int i = 0; i < 4; i++) {
        int row = row0 + ty * 4 + i;
        if (row < NN) {
            size_t b = (size_t)row * HD;
            FS[b + tx] = acc[i][0]; FS[b + tx + 64] = acc[i][1]; FS[b + tx + 128] = acc[i][2];
            FD[b + tx] = acc[i][3]; FD[b + tx + 64] = acc[i][4]; FD[b + tx + 128] = acc[i][5];
        }
    }
}

// ---------------- per-edge attention logits (CSR order) ----------------
__global__ __launch_bounds__(256) void k_edge_logits(const int* __restrict__ csr_src,
                                                     const int* __restrict__ csr_dst,
                                                     const float* __restrict__ FS,
                                                     const float* __restrict__ FD,
                                                     const float* __restrict__ A,
                                                     float* __restrict__ logits) {
    int p = blockIdx.x * 4 + (threadIdx.x >> 6);
    if (p >= EE) return;
    int lane = threadIdx.x & 63;
    int u = csr_src[p], v = csr_dst[p];
    float a0 = A[lane], a1 = A[64 + lane], a2 = A[128 + lane];
    size_t bu = (size_t)u * HD, bv = (size_t)v * HD;
    float s0 = FS[bu + lane]       + FD[bv + lane];
    float s1 = FS[bu + 64 + lane]  + FD[bv + 64 + lane];
    float s2 = FS[bu + 128 + lane] + FD[bv + 128 + lane];
    s0 = s0 > 0.f ? s0 : 0.2f * s0;
    s1 = s1 > 0.f ? s1 : 0.2f * s1;
    s2 = s2 > 0.f ? s2 : 0.2f * s2;
    float l0 = wsum(s0 * a0), l1 = wsum(s1 * a1), l2 = wsum(s2 * a2);
    if (lane == 0) {
        logits[p * 3 + 0] = l0;
        logits[p * 3 + 1] = l1;
        logits[p * 3 + 2] = l2;
    }
}

// ---------------- per-node softmax + aggregate (wave per node) ----------------
template <bool FINAL>
__global__ __launch_bounds__(256) void k_aggregate(const int* __restrict__ row_ptr,
                                                   const int* __restrict__ csr_src,
                                                   const float* __restrict__ logits,
                                                   const float* __restrict__ FS,
                                                   const float* __restrict__ bias,
                                                   float* __restrict__ OUT,
                                                   const int* __restrict__ graph_ids,
                                                   float* __restrict__ gsum,
                                                   int* __restrict__ gcnt) {
    int v = blockIdx.x * 4 + (threadIdx.x >> 6);
    if (v >= NN) return;
    int lane = threadIdx.x & 63;
    int start = row_ptr[v], end = row_ptr[v + 1];
    float acc0 = 0.f, acc1 = 0.f, acc2 = 0.f;
    if (end > start) {
        float m0 = -1e30f, m1 = -1e30f, m2 = -1e30f;
        for (int p = start + lane; p < end; p += 64) {
            m0 = fmaxf(m0, logits[p * 3 + 0]);
            m1 = fmaxf(m1, logits[p * 3 + 1]);
            m2 = fmaxf(m2, logits[p * 3 + 2]);
        }
        m0 = wmax(m0); m1 = wmax(m1); m2 = wmax(m2);
        float s0 = 0.f, s1 = 0.f, s2 = 0.f;
        for (int p = start + lane; p < end; p += 64) {
            s0 += expf(logits[p * 3 + 0] - m0);
            s1 += expf(logits[p * 3 + 1] - m1);
            s2 += expf(logits[p * 3 + 2] - m2);
        }
        s0 = wsum(s0); s1 = wsum(s1); s2 = wsum(s2);
        float i0 = 1.f / fmaxf(s0, 1e-9f);
        float i1 = 1.f / fmaxf(s1, 1e-9f);
        float i2 = 1.f / fmaxf(s2, 1e-9f);
        for (int p = start; p < end; p++) {
            float w0 = expf(logits[p * 3 + 0] - m0) * i0;
            float w1 = expf(logits[p * 3 + 1] - m1) * i1;
            float w2 = expf(logits[p * 3 + 2] - m2) * i2;
            int u = csr_src[p];
            size_t b = (size_t)u * HD;
            acc0 += w0 * FS[b + lane];
            acc1 += w1 * FS[b + 64 + lane];
            acc2 += w2 * FS[b + 128 + lane];
        }
    }
    if (!FINAL) {
        size_t b = (size_t)v * HD;
        OUT[b + lane]       = acc0 + bias[lane];
        OUT[b + 64 + lane]  = acc1 + bias[64 + lane];
        OUT[b + 128 + lane] = acc2 + bias[128 + lane];
    } else {
        int g = graph_ids[v];
        float val = (acc0 + acc1 + acc2 + bias[lane] + bias[64 + lane] + bias[128 + lane]) * (1.f / 3.f);
        atomicAdd(&gsum[g * 64 + lane], val);
        if (lane == 0) atomicAdd(&gcnt[g], 1);
    }
}

// ---------------- head: graph mean + pattern branch + classifier ----------------
__global__ __launch_bounds__(256) void k_head(const float* __restrict__ gsum, const int* __restrict__ gcnt,
                                              const float* __restrict__ p1, const float* __restrict__ p2,
                                              const float* __restrict__ p3,
                                              const float* __restrict__ Wex, const float* __restrict__ bex,
                                              const float* __restrict__ Wpat, const float* __restrict__ bpat,
                                              const float* __restrict__ Wc1, const float* __restrict__ bc1,
                                              const float* __restrict__ Wc2, const float* __restrict__ bc2,
                                              const float* __restrict__ Wc3, const float* __restrict__ bc3,
                                              float* __restrict__ out) {
    __shared__ float EX[64 * 96];    // also reused for T1 (4096) + T2 (2048)
    __shared__ float XC[64 * 128];
    int tid = threadIdx.x;
    // stage 1: EX = [p1@Wex+bex | p2@Wex+bex | p3@Wex+bex]
    for (int idx = tid; idx < 64 * 96; idx += 256) {
        int g = idx / 96, j = idx - g * 96;
        const float* pp = (j < 32) ? p1 : ((j < 64) ? p2 : p3);
        int jj = j & 31;
        float acc = bex[jj];
        for (int k = 0; k < 64; k++) acc += pp[g * 64 + k] * Wex[k * 32 + jj];
        EX[idx] = acc;
    }
    // gnn_out into XC[:, :64]
    for (int idx = tid; idx < 64 * 64; idx += 256) {
        int g = idx >> 6, d = idx & 63;
        float c = (float)gcnt[g];
        XC[g * 128 + d] = gsum[idx] / fmaxf(c, 1.f);
    }
    __syncthreads();
    // stage 2: px into XC[:, 64:]
    for (int idx = tid; idx < 64 * 64; idx += 256) {
        int g = idx >> 6, j = idx & 63;
        float acc = bpat[j];
        for (int k = 0; k < 96; k++) acc += EX[g * 96 + k] * Wpat[k * 64 + j];
        XC[g * 128 + 64 + j] = acc > 0.f ? acc : 0.01f * acc;
    }
    __syncthreads();
    // stage 3: T1 = lrelu(XC @ Wc1 + bc1)
    float* T1 = EX;
    for (int idx = tid; idx < 64 * 64; idx += 256) {
        int g = idx >> 6, j = idx & 63;
        float acc = bc1[j];
        for (int k = 0; k < 128; k++) acc += XC[g * 128 + k] * Wc1[k * 64 + j];
        T1[idx] = acc > 0.f ? acc : 0.01f * acc;
    }
    __syncthreads();
    // stage 4: T2 = lrelu(T1 @ Wc2 + bc2)
    float* T2 = EX + 4096;
    for (int idx = tid; idx < 64 * 32; idx += 256) {
        int g = idx >> 5, j = idx & 31;
        float acc = bc2[j];
        for (int k = 0; k < 64; k++) acc += T1[g * 64 + k] * Wc2[k * 32 + j];
        T2[idx] = acc > 0.f ? acc : 0.01f * acc;
    }
    __syncthreads();
    // stage 5: out = T2 @ Wc3 + bc3
    for (int idx = tid; idx < 64 * 2; idx += 256) {
        int g = idx >> 1, c = idx & 1;
        float acc = bc3[c];
        for (int k = 0; k < 32; k++) acc += T2[g * 32 + k] * Wc3[k * 2 + c];
        out[idx] = acc;
    }
}

extern "C" void kernel_launch(void* const* d_in, const int* in_sizes, int n_in,
                              void* d_out, int out_size, void* d_ws, size_t ws_size,
                              hipStream_t stream) {
    const float* X0  = (const float*)d_in[0];
    const int*   src = (const int*)d_in[1];
    const int*   dst = (const int*)d_in[2];
    const int*   gid = (const int*)d_in[3];
    const float* p1  = (const float*)d_in[4];
    const float* p2  = (const float*)d_in[5];
    const float* p3  = (const float*)d_in[6];
    const float* W1s = (const float*)d_in[7],  *W1d = (const float*)d_in[8];
    const float* a1  = (const float*)d_in[9],  *b1  = (const float*)d_in[10];
    const float* W2s = (const float*)d_in[11], *W2d = (const float*)d_in[12];
    const float* a2  = (const float*)d_in[13], *b2  = (const float*)d_in[14];
    const float* W3s = (const float*)d_in[15], *W3d = (const float*)d_in[16];
    const float* a3  = (const float*)d_in[17], *b3  = (const float*)d_in[18];
    const float* Wex = (const float*)d_in[19], *bex = (const float*)d_in[20];
    const float* Wpat= (const float*)d_in[21], *bpat= (const float*)d_in[22];
    const float* Wc1 = (const float*)d_in[23], *bc1 = (const float*)d_in[24];
    const float* Wc2 = (const float*)d_in[25], *bc2 = (const float*)d_in[26];
    const float* Wc3 = (const float*)d_in[27], *bc3 = (const float*)d_in[28];
    float* out = (float*)d_out;

    char* ws = (char*)d_ws;
    size_t off = 0;
    auto alloc = [&](size_t bytes) -> char* {
        char* p = ws + off;
        off = (off + bytes + 255) & ~(size_t)255;
        return p;
    };
    float* FS = (float*)alloc((size_t)NN * HD * 4);
    float* FD = (float*)alloc((size_t)NN * HD * 4);
    float* HA = (float*)alloc((size_t)NN * HD * 4);
    float* HB = (float*)alloc((size_t)NN * HD * 4);
    float* LG = (float*)alloc((size_t)EE * 3 * 4);
    int* row_ptr = (int*)alloc((size_t)(NN + 1) * 4);
    int* csr_src = (int*)alloc((size_t)EE * 4);
    int* csr_dst = (int*)alloc((size_t)EE * 4);
    int* bsums   = (int*)alloc(64 * 4);
    // zeroed region (one memset): counts | cursor | gsum | gcnt
    char* zbase = ws + off;
    int*   counts = (int*)alloc((size_t)NN * 4);
    int*   cursor = (int*)alloc((size_t)NN * 4);
    float* gsum   = (float*)alloc((size_t)GG * 64 * 4);
    int*   gcnt   = (int*)alloc((size_t)GG * 4);
    size_t zbytes = (size_t)((ws + off) - zbase);

    hipMemsetAsync(zbase, 0, zbytes, stream);

    int ebl = (EE + 255) / 256;
    int nb  = (NN + 1023) / 1024;
    k_count<<<ebl, 256, 0, stream>>>(dst, counts);
    k_scan_block<<<nb, 1024, 0, stream>>>(counts, row_ptr, bsums);
    k_scan_top<<<1, 64, 0, stream>>>(bsums, nb);
    k_scan_add<<<nb, 1024, 0, stream>>>(row_ptr, bsums);
    k_scatter<<<ebl, 256, 0, stream>>>(src, dst, row_ptr, cursor, csr_src, csr_dst);

    int gblk  = (NN + 15) / 16;
    int eblk4 = (EE + 3) / 4;
    int nblk4 = (NN + 3) / 4;

    // layer 1 (K = 128)
    k_gemm_dual<128><<<gblk, 256, 0, stream>>>(X0, W1s, W1d, FS, FD);
    k_edge_logits<<<eblk4, 256, 0, stream>>>(csr_src, csr_dst, FS, FD, a1, LG);
    k_aggregate<false><<<nblk4, 256, 0, stream>>>(row_ptr, csr_src, LG, FS, b1, HA,
                                                  nullptr, nullptr, nullptr);
    // layer 2 (K = 192)
    k_gemm_dual<192><<<gblk, 256, 0, stream>>>(HA, W2s, W2d, FS, FD);
    k_edge_logits<<<eblk4, 256, 0, stream>>>(csr_src, csr_dst, FS, FD, a2, LG);
    k_aggregate<false><<<nblk4, 256, 0, stream>>>(row_ptr, csr_src, LG, FS, b2, HB,
                                                  nullptr, nullptr, nullptr);
    // layer 3 (K = 192), fused head-mean + graph-sum
    k_gemm_dual<192><<<gblk, 256, 0, stream>>>(HB, W3s, W3d, FS, FD);
    k_edge_logits<<<eblk4, 256, 0, stream>>>(csr_src, csr_dst, FS, FD, a3, LG);
    k_aggregate<true><<<nblk4, 256, 0, stream>>>(row_ptr, csr_src, LG, FS, b3, nullptr,
                                                 gid, gsum, gcnt);

    k_head<<<1, 256, 0, stream>>>(gsum, gcnt, p1, p2, p3, Wex, bex, Wpat, bpat,
                                  Wc1, bc1, Wc2, bc2, Wc3, bc3, out);
}